// Round 14
// baseline (159.460 us; speedup 1.0000x reference)
//
#include <hip/hip_runtime.h>
#include <hip/hip_bf16.h>
#include <stdint.h>

// Problem constants
#define BB  2
#define LL  1024
#define DMM 768
#define DII 1536
#define NSS 16
#define DTRR 48
#define XZN (2*DII)        // 3072
#define NROWS (BB*LL)      // 2048
#define N2 1664            // padded N for combined GEMM2 (1536 dmod + 32 B/C + 96 pad)

// chunked scan: one thread per (b, d, chunk), 16 n-states in registers
#define CHUNKS 64
#define CHLEN  (LL/CHUNKS)          // 16
#define NCH    (BB*DII*NSS)         // 49152 channels

typedef _Float16 h16;
typedef __attribute__((ext_vector_type(4))) _Float16 h16x4;
typedef __attribute__((ext_vector_type(8))) _Float16 h16x8;
typedef __attribute__((ext_vector_type(4))) float f32x4;

typedef const __attribute__((address_space(1))) uint32_t gau32;
typedef __attribute__((address_space(3))) uint32_t lau32;
#define GLL16(gp, lp) __builtin_amdgcn_global_load_lds((gau32*)(gp), (lau32*)(lp), 16, 0, 0)

__device__ __forceinline__ float dspf(float x) {
    return 0.25f * (x + sqrtf(x*x + 4.0f));
}
__device__ __forceinline__ float clampf(float x, float lo, float hi) {
    return fminf(fmaxf(x, lo), hi);
}

// ---------------------------------------------------------------------------
// K0: merged prep = {W_in,W_out -> f16 (vectorized x4)} + {W2/bias2} + {norm}
// ---------------------------------------------------------------------------
#define CVT_BLOCKS ((XZN*DMM + DMM*DII)/4/256)  // 3456
#define W2_BLOCKS  N2                           // 1664
#define NORM_BLOCKS (NROWS/4)                   // 512

__global__ __launch_bounds__(256) void k_prep(
    const float* __restrict__ W_in,  h16* __restrict__ WINH,
    const float* __restrict__ W_out, h16* __restrict__ WOH,
    const float* __restrict__ W_x,   const float* __restrict__ b_x,
    const float* __restrict__ W_dt,  const float* __restrict__ b_dt,
    h16* __restrict__ W2, float* __restrict__ bias2,
    const float* __restrict__ hs, const float* __restrict__ gamma,
    h16* __restrict__ HSNH)
{
    __shared__ float wd[DTRR];
    int blk = blockIdx.x;
    int tid = threadIdx.x;

    if (blk < CVT_BLOCKS) {
        int i4 = blk * 256 + tid;
        const int n14 = (XZN * DMM) / 4;
        const float* src; h16* dst; int o4;
        if (i4 < n14) { src = W_in;  dst = WINH; o4 = i4; }
        else          { src = W_out; dst = WOH;  o4 = i4 - n14; }
        float4 v = *(const float4*)&src[(size_t)o4 * 4];
        h16x4 o = { (h16)v.x, (h16)v.y, (h16)v.z, (h16)v.w };
        *(h16x4*)&dst[(size_t)o4 * 4] = o;
        return;
    }
    blk -= CVT_BLOCKS;
    if (blk < W2_BLOCKS) {
        int i = blk;
        if (i < DII) {
            if (tid < DTRR) wd[tid] = W_dt[i * DTRR + tid];
            __syncthreads();
            for (int j = tid; j < DII; j += 256) {
                float s = 0.f;
                #pragma unroll
                for (int k = 0; k < DTRR; ++k) s = fmaf(wd[k], W_x[(size_t)k * DII + j], s);
                W2[(size_t)i * DII + j] = (h16)s;
            }
            if (tid == 0) {
                float s = b_dt[i];
                for (int k = 0; k < DTRR; ++k) s = fmaf(wd[k], b_x[k], s);
                bias2[i] = s;
            }
        } else if (i < DII + 2 * NSS) {
            int r = i - DII;
            for (int j = tid; j < DII; j += 256)
                W2[(size_t)i * DII + j] = (h16)W_x[(size_t)(DTRR + r) * DII + j];
            if (tid == 0) bias2[i] = b_x[DTRR + r];
        } else {
            for (int j = tid; j < DII; j += 256) W2[(size_t)i * DII + j] = (h16)0.f;
            if (tid == 0) bias2[i] = 0.f;
        }
        return;
    }
    blk -= W2_BLOCKS;
    // norm: wave-per-row, 4 rows/block
    int row  = blk * 4 + (tid >> 6);
    int lane = tid & 63;
    const float* p = hs + (size_t)row * DMM;
    float4 v0 = *(const float4*)&p[lane * 4];
    float4 v1 = *(const float4*)&p[256 + lane * 4];
    float4 v2 = *(const float4*)&p[512 + lane * 4];
    float s = v0.x+v0.y+v0.z+v0.w + v1.x+v1.y+v1.z+v1.w + v2.x+v2.y+v2.z+v2.w;
    #pragma unroll
    for (int off = 32; off > 0; off >>= 1) s += __shfl_xor(s, off);
    float mean = s * (1.0f / (float)DMM);
    float vv = 0.f;
    #pragma unroll
    for (int q = 0; q < 4; ++q) {
        float d0 = ((const float*)&v0)[q] - mean; vv += d0*d0;
        float d1 = ((const float*)&v1)[q] - mean; vv += d1*d1;
        float d2 = ((const float*)&v2)[q] - mean; vv += d2*d2;
    }
    #pragma unroll
    for (int off = 32; off > 0; off >>= 1) vv += __shfl_xor(vv, off);
    float var = vv * (1.0f / (float)DMM);
    float k = rintf(log2f(sqrtf(var + 1e-9f)));
    k = fmaxf(k, 0.f);
    float scale = exp2f(-k);
    float4 g0 = *(const float4*)&gamma[lane * 4];
    float4 g1 = *(const float4*)&gamma[256 + lane * 4];
    float4 g2 = *(const float4*)&gamma[512 + lane * 4];
    h16* o = HSNH + (size_t)row * DMM;
    #pragma unroll
    for (int q = 0; q < 4; ++q) {
        o[lane*4 + q]       = (h16)((((const float*)&v0)[q] - mean) * scale * ((const float*)&g0)[q]);
        o[256 + lane*4 + q] = (h16)((((const float*)&v1)[q] - mean) * scale * ((const float*)&g1)[q]);
        o[512 + lane*4 + q] = (h16)((((const float*)&v2)[q] - mean) * scale * ((const float*)&g2)[q]);
    }
}

// ---------------------------------------------------------------------------
// MFMA f16 GEMM, 128x128 tile, BK=64, double-buffered LDS, vmcnt(8), XCD swz,
// setprio(1) around the MFMA cluster (2 resident blocks/CU -> phase diversity).
// EPI: 0 = plain out; 1 = resid + clip(acc+bias)*rg; 2 = gate() on cols>=DII.
// ---------------------------------------------------------------------------
template<int EPI, typename OutT>
__global__ __launch_bounds__(256) void k_gemm128(
    const h16* __restrict__ A, int lda,
    const h16* __restrict__ Bw, int ldb,
    const float* __restrict__ bias,
    OutT* __restrict__ C, int ldc, int K,
    const float* __restrict__ resid, const float* __restrict__ rgate)
{
    __shared__ __align__(16) h16 As[2][128 * 64];
    __shared__ __align__(16) h16 Bs[2][128 * 64];
    const int tid  = threadIdx.x;
    const int lane = tid & 63;
    const int wv   = tid >> 6;

    const int nwg = gridDim.x * gridDim.y;
    const int bid = blockIdx.y * gridDim.x + blockIdx.x;
    const int cpx = nwg >> 3;
    const int swz = (bid & 7) * cpx + (bid >> 3);
    const int bxi = swz % gridDim.x, byi = swz / gridDim.x;

    const int bm = byi * 128, bn = bxi * 128;
    const int wr = wv >> 1, wc = wv & 1;

    f32x4 acc[4][4] = {};

    const int srow = lane >> 3;
    const int kbl  = ((lane & 7) ^ srow) * 8;
    const int KT = K / 64;

#define STAGE128(dstbuf, k0) do { \
    _Pragma("unroll") \
    for (int q = 0; q < 4; ++q) { \
        int row_ = (wv * 4 + q) * 8 + srow; \
        GLL16(A  + (size_t)(bm + row_) * lda + (k0) + kbl, &As[dstbuf][(wv*4+q)*8*64]); \
        GLL16(Bw + (size_t)(bn + row_) * ldb + (k0) + kbl, &Bs[dstbuf][(wv*4+q)*8*64]); \
    } } while (0)

    STAGE128(0, 0);
    int buf = 0;
    const int r16 = lane & 15, kq = lane >> 4;

    for (int kt = 0; kt < KT; ++kt) {
        if (kt + 1 < KT) {
            STAGE128(buf ^ 1, (kt + 1) * 64);
            asm volatile("s_waitcnt vmcnt(8)" ::: "memory");
        } else {
            asm volatile("s_waitcnt vmcnt(0)" ::: "memory");
        }
        __syncthreads();
        __builtin_amdgcn_s_setprio(1);
        #pragma unroll
        for (int kk = 0; kk < 2; ++kk) {
            h16x8 af[4], bf[4];
            #pragma unroll
            for (int i = 0; i < 4; ++i) {
                int rowA = wr * 64 + i * 16 + r16;
                af[i] = *(const h16x8*)&As[buf][rowA * 64 + (((kk*4 + kq) ^ (rowA & 7)) << 3)];
            }
            #pragma unroll
            for (int j = 0; j < 4; ++j) {
                int rowB = wc * 64 + j * 16 + r16;
                bf[j] = *(const h16x8*)&Bs[buf][rowB * 64 + (((kk*4 + kq) ^ (rowB & 7)) << 3)];
            }
            #pragma unroll
            for (int i = 0; i < 4; ++i)
                #pragma unroll
                for (int j = 0; j < 4; ++j)
                    acc[i][j] = __builtin_amdgcn_mfma_f32_16x16x32_f16(af[i], bf[j], acc[i][j], 0, 0, 0);
        }
        __builtin_amdgcn_s_setprio(0);
        __syncthreads();
        buf ^= 1;
    }
#undef STAGE128

    const int r4 = (lane >> 4) * 4;
    const int cn = lane & 15;
    float rg = 0.f;
    if (EPI == 1) rg = rgate[0];
    #pragma unroll
    for (int i = 0; i < 4; ++i) {
        #pragma unroll
        for (int j = 0; j < 4; ++j) {
            int col = bn + wc * 64 + j * 16 + cn;
            float bv = bias[col];
            #pragma unroll
            for (int r = 0; r < 4; ++r) {
                int row = bm + wr * 64 + i * 16 + r4 + r;
                float v = acc[i][j][r] + bv;
                if (EPI == 1) {
                    v = clampf(v, -32000.f, 32000.f);
                    v = resid[(size_t)row * ldc + col] + v * rg;
                }
                if (EPI == 2) {
                    if (col >= DII) v = 0.5f * (1.0f + v * rsqrtf(v * v + 1.0f));
                }
                C[(size_t)row * ldc + col] = (OutT)v;
            }
        }
    }
}

// ---------------------------------------------------------------------------
// MFMA f16 GEMM, 64x64 tile (proven) for the small-N gemm3, with setprio.
// ---------------------------------------------------------------------------
template<int EPI, typename OutT>
__global__ __launch_bounds__(256) void k_gemm64(
    const h16* __restrict__ A, int lda,
    const h16* __restrict__ Bw, int ldb,
    const float* __restrict__ bias,
    OutT* __restrict__ C, int ldc, int K,
    const float* __restrict__ resid, const float* __restrict__ rgate)
{
    __shared__ __align__(16) h16 As[2][64 * 64];
    __shared__ __align__(16) h16 Bs[2][64 * 64];
    const int tid  = threadIdx.x;
    const int lane = tid & 63;
    const int wv   = tid >> 6;

    const int nwg = gridDim.x * gridDim.y;
    const int bid = blockIdx.y * gridDim.x + blockIdx.x;
    const int cpx = nwg >> 3;
    const int swz = (bid & 7) * cpx + (bid >> 3);
    const int bxi = swz % gridDim.x, byi = swz / gridDim.x;

    const int bm = byi * 64, bn = bxi * 64;
    const int wr = wv >> 1, wc = wv & 1;

    f32x4 acc[2][2] = {};

    const int srow = lane >> 3;
    const int kbl  = ((lane & 7) ^ srow) * 8;
    const int KT = K / 64;

    #pragma unroll
    for (int q = 0; q < 2; ++q) {
        int row = (wv * 2 + q) * 8 + srow;
        GLL16(A  + (size_t)(bm + row) * lda + kbl, &As[0][(wv*2+q)*8*64]);
        GLL16(Bw + (size_t)(bn + row) * ldb + kbl, &Bs[0][(wv*2+q)*8*64]);
    }

    int buf = 0;
    for (int kt = 0; kt < KT; ++kt) {
        if (kt + 1 < KT) {
            int k0 = (kt + 1) * 64;
            #pragma unroll
            for (int q = 0; q < 2; ++q) {
                int row = (wv * 2 + q) * 8 + srow;
                GLL16(A  + (size_t)(bm + row) * lda + k0 + kbl, &As[buf^1][(wv*2+q)*8*64]);
                GLL16(Bw + (size_t)(bn + row) * ldb + k0 + kbl, &Bs[buf^1][(wv*2+q)*8*64]);
            }
            asm volatile("s_waitcnt vmcnt(4)" ::: "memory");
        } else {
            asm volatile("s_waitcnt vmcnt(0)" ::: "memory");
        }
        __syncthreads();

        const int r16 = lane & 15, kq = lane >> 4;
        __builtin_amdgcn_s_setprio(1);
        #pragma unroll
        for (int kk = 0; kk < 2; ++kk) {
            h16x8 af[2], bf[2];
            #pragma unroll
            for (int i = 0; i < 2; ++i) {
                int rowA = wr * 32 + i * 16 + r16;
                af[i] = *(const h16x8*)&As[buf][rowA * 64 + (((kk*4 + kq) ^ (rowA & 7)) << 3)];
            }
            #pragma unroll
            for (int j = 0; j < 2; ++j) {
                int rowB = wc * 32 + j * 16 + r16;
                bf[j] = *(const h16x8*)&Bs[buf][rowB * 64 + (((kk*4 + kq) ^ (rowB & 7)) << 3)];
            }
            #pragma unroll
            for (int i = 0; i < 2; ++i)
                #pragma unroll
                for (int j = 0; j < 2; ++j)
                    acc[i][j] = __builtin_amdgcn_mfma_f32_16x16x32_f16(af[i], bf[j], acc[i][j], 0, 0, 0);
        }
        __builtin_amdgcn_s_setprio(0);
        __syncthreads();
        buf ^= 1;
    }

    const int r4 = (lane >> 4) * 4;
    const int cn = lane & 15;
    float rg = 0.f;
    if (EPI == 1) rg = rgate[0];
    #pragma unroll
    for (int i = 0; i < 2; ++i) {
        #pragma unroll
        for (int j = 0; j < 2; ++j) {
            int col = bn + wc * 32 + j * 16 + cn;
            float bv = bias[col];
            #pragma unroll
            for (int r = 0; r < 4; ++r) {
                int row = bm + wr * 32 + i * 16 + r4 + r;
                float v = acc[i][j][r] + bv;
                if (EPI == 1) {
                    v = clampf(v, -32000.f, 32000.f);
                    v = resid[(size_t)row * ldc + col] + v * rg;
                }
                C[(size_t)row * ldc + col] = (OutT)v;
            }
        }
    }
}

// ---------------------------------------------------------------------------
// K3: depthwise causal conv (f16 in) + dsp -> f16 xact, 8 channels/thread
// ---------------------------------------------------------------------------
__global__ __launch_bounds__(256) void k_conv(const h16* __restrict__ xz,
                                              const float* __restrict__ cw,
                                              const float* __restrict__ cb,
                                              h16* __restrict__ xacth)
{
    int idx = blockIdx.x * 256 + threadIdx.x;       // over NROWS * (DII/8)
    if (idx >= NROWS * (DII / 8)) return;
    int c8 = idx % (DII / 8);
    int bl = idx / (DII / 8);
    int l = bl % LL;
    int b = bl / LL;
    int c0 = c8 * 8;

    float acc[8];
    float4 wv[8];
    #pragma unroll
    for (int j = 0; j < 8; ++j) {
        acc[j] = cb[c0 + j];
        wv[j] = *(const float4*)&cw[(c0 + j) * 4];
    }
    #pragma unroll
    for (int t = 0; t < 4; ++t) {
        int ls = l - 3 + t;
        if (ls >= 0) {
            h16x8 xv = *(const h16x8*)&xz[(size_t)(b * LL + ls) * XZN + c0];
            #pragma unroll
            for (int j = 0; j < 8; ++j)
                acc[j] = fmaf((float)xv[j], ((const float*)&wv[j])[t], acc[j]);
        }
    }
    h16x8 o;
    #pragma unroll
    for (int j = 0; j < 8; ++j) o[j] = (h16)dspf(acc[j]);
    *(h16x8*)&xacth[(size_t)bl * DII + c0] = o;
}

// ---------------------------------------------------------------------------
// Chunked scan, f16 state, l-loop unroll 8 (deeper MLP; p1/p3 latency-bound,
// VGPR headroom large at 36 regs).
// a = clip(base+dm,0,32767)*2^-s == fma(dm, p2c, base*p2c) (clip never binds).
// ---------------------------------------------------------------------------
__device__ __forceinline__ void load_setup(const float* __restrict__ basenum,
                                           const int* __restrict__ shifts,
                                           int d, float* baseP, float* p2c) {
    const float4* bp = (const float4*)(basenum + (size_t)d * NSS);
    const int4*   sp = (const int4*)(shifts + (size_t)d * NSS);
    #pragma unroll
    for (int q = 0; q < 4; ++q) {
        float4 bv = bp[q]; int4 sv = sp[q];
        p2c[q*4+0] = exp2f(-(float)sv.x);
        p2c[q*4+1] = exp2f(-(float)sv.y);
        p2c[q*4+2] = exp2f(-(float)sv.z);
        p2c[q*4+3] = exp2f(-(float)sv.w);
        baseP[q*4+0] = bv.x * p2c[q*4+0];
        baseP[q*4+1] = bv.y * p2c[q*4+1];
        baseP[q*4+2] = bv.z * p2c[q*4+2];
        baseP[q*4+3] = bv.w * p2c[q*4+3];
    }
}

__global__ __launch_bounds__(256) void k_scan_p1(
    const h16* __restrict__ dmbc,      // (B*L, N2) f16: [dmod 1536 | B 16 | C 16 | pad]
    const h16* __restrict__ xacth,     // (B*L, DI)
    const float* __restrict__ basenum, // (DI, NS)
    const int*   __restrict__ shifts,  // (DI, NS)
    h16* __restrict__ stA, h16* __restrict__ stH)
{
    int bc   = blockIdx.x / 6;              // b*CHUNKS + chunk  (uniform)
    int dblk = blockIdx.x % 6;
    int d    = dblk * 256 + threadIdx.x;
    int b    = bc / CHUNKS;
    int chunk= bc % CHUNKS;

    float baseP[16], p2c[16], h[16], A[16];
    load_setup(basenum, shifts, d, baseP, p2c);
    #pragma unroll
    for (int n = 0; n < 16; ++n) { h[n] = 0.f; A[n] = 1.f; }

    int row0 = b * LL + chunk * CHLEN;
    #pragma unroll 8
    for (int l = 0; l < CHLEN; ++l) {
        int row = row0 + l;
        float dm = (float)dmbc[(size_t)row * N2 + d];
        float xv = (float)xacth[(size_t)row * DII + d];
        float common = xv * (dspf(dm) * 0.1f);
        const h16x8* Bp = (const h16x8*)(dmbc + (size_t)row * N2 + DII);
        h16x8 b0 = Bp[0], b1 = Bp[1];
        float Bv[16];
        #pragma unroll
        for (int n = 0; n < 8; ++n) { Bv[n] = (float)b0[n]; Bv[8+n] = (float)b1[n]; }
        #pragma unroll
        for (int n = 0; n < 16; ++n) {
            float a = fmaf(dm, p2c[n], baseP[n]);
            h[n] = fmaf(a, h[n], common * Bv[n]);
            A[n] *= a;
        }
    }
    size_t sb = ((size_t)bc * DII + d) * 16;
    h16x8 a0, a1, h0, h1;
    #pragma unroll
    for (int n = 0; n < 8; ++n) {
        a0[n] = (h16)A[n];   a1[n] = (h16)A[8+n];
        h0[n] = (h16)h[n];   h1[n] = (h16)h[8+n];
    }
    *(h16x8*)&stA[sb]     = a0;
    *(h16x8*)&stA[sb + 8] = a1;
    *(h16x8*)&stH[sb]     = h0;
    *(h16x8*)&stH[sb + 8] = h1;
}

__global__ __launch_bounds__(64) void k_scan_p2(h16* __restrict__ stA,
                                                const h16* __restrict__ stH)
{
    int ch = blockIdx.x * 64 + threadIdx.x;    // b*(DII*NSS) + d*16 + n
    int b  = ch / (DII * NSS);
    int rem = ch - b * (DII * NSS);
    float hin = 0.f;
    #pragma unroll 4
    for (int c = 0; c < CHUNKS; ++c) {
        size_t idx = ((size_t)(b * CHUNKS + c) * (DII * NSS)) + rem;
        float a = (float)stA[idx], hh = (float)stH[idx];
        stA[idx] = (h16)hin;
        hin = fmaf(a, hin, hh);
    }
}

__global__ __launch_bounds__(256) void k_scan_p3(
    const h16* __restrict__ dmbc,
    const h16* __restrict__ xacth,
    const h16* __restrict__ xz,        // z-half already gate-transformed
    const float* __restrict__ basenum,
    const int*   __restrict__ shifts,
    const h16* __restrict__ stA,
    h16* __restrict__ ygh)             // (B*L, DI) = y * gate(z), f16
{
    int bc   = blockIdx.x / 6;
    int dblk = blockIdx.x % 6;
    int d    = dblk * 256 + threadIdx.x;
    int b    = bc / CHUNKS;
    int chunk= bc % CHUNKS;

    float baseP[16], p2c[16], h[16];
    load_setup(basenum, shifts, d, baseP, p2c);
    size_t sb = ((size_t)bc * DII + d) * 16;
    {
        h16x8 p0 = *(const h16x8*)&stA[sb];
        h16x8 p1 = *(const h16x8*)&stA[sb + 8];
        #pragma unroll
        for (int n = 0; n < 8; ++n) { h[n] = (float)p0[n]; h[8+n] = (float)p1[n]; }
    }

    int row0 = b * LL + chunk * CHLEN;
    #pragma unroll 8
    for (int l = 0; l < CHLEN; ++l) {
        int row = row0 + l;
        float dm = (float)dmbc[(size_t)row * N2 + d];
        float xv = (float)xacth[(size_t)row * DII + d];
        float common = xv * (dspf(dm) * 0.1f);
        const h16x8* Bp = (const h16x8*)(dmbc + (size_t)row * N2 + DII);
        h16x8 b0 = Bp[0], b1 = Bp[1], c0 = Bp[2], c1 = Bp[3];
        float Bv[16], Cv[16];
        #pragma unroll
        for (int n = 0; n < 8; ++n) {
            Bv[n] = (float)b0[n]; Bv[8+n] = (float)b1[n];
            Cv[n] = (float)c0[n]; Cv[8+n] = (float)c1[n];
        }
        float y = 0.f;
        #pragma unroll
        for (int n = 0; n < 16; ++n) {
            float a = fmaf(dm, p2c[n], baseP[n]);
            h[n] = fmaf(a, h[n], common * Bv[n]);
            float hc = clampf(h[n], -32000.f, 32000.f);
            y = fmaf(hc, Cv[n], y);
        }
        float gate = (float)xz[(size_t)row * XZN + DII + d];   // pre-gated
        ygh[(size_t)row * DII + d] = (h16)(y * gate);
    }
}

// ---------------------------------------------------------------------------
extern "C" void kernel_launch(void* const* d_in, const int* in_sizes, int n_in,
                              void* d_out, int out_size, void* d_ws, size_t ws_size,
                              hipStream_t stream) {
    const float* hs        = (const float*)d_in[0];
    const float* gamma     = (const float*)d_in[1];
    const float* W_in      = (const float*)d_in[2];
    const float* b_in      = (const float*)d_in[3];
    const float* conv_w    = (const float*)d_in[4];
    const float* conv_b    = (const float*)d_in[5];
    const float* W_x       = (const float*)d_in[6];
    const float* b_x       = (const float*)d_in[7];
    const float* W_dt      = (const float*)d_in[8];
    const float* b_dt      = (const float*)d_in[9];
    const float* W_out     = (const float*)d_in[10];
    const float* b_out     = (const float*)d_in[11];
    const float* base_dec  = (const float*)d_in[12];
    const float* res_gate  = (const float*)d_in[13];
    const int*   dec_shift = (const int*)d_in[14];

    // workspace layout (bytes)
    char* w = (char*)d_ws;
    h16*   XZH   = (h16*)w;    w += (size_t)NROWS * XZN * 2;   // 12.6 MB (x | gate(z))
    h16*   XACTH = (h16*)w;    w += (size_t)NROWS * DII * 2;   //  6.3 MB
    h16*   DMBCH = (h16*)w;    w += (size_t)NROWS * N2  * 2;   //  6.8 MB
    h16*   W2H   = (h16*)w;    w += (size_t)N2 * DII * 2;      //  5.1 MB
    h16*   WOH   = (h16*)w;    w += (size_t)DMM * DII * 2;     //  2.4 MB
    float* BIAS2 = (float*)w;  w += 8192;
    h16*   YGH   = (h16*)w;    w += (size_t)NROWS * DII * 2;   //  6.3 MB
    h16*   HSNH  = (h16*)w;    w += (size_t)NROWS * DMM * 2;   //  3.1 MB
    h16*   WINH  = (h16*)w;    w += (size_t)XZN * DMM * 2;     //  4.7 MB
    h16*   STA   = (h16*)w;    w += (size_t)BB * CHUNKS * DII * NSS * 2;  // 6.3 MB
    h16*   STH   = (h16*)w;    w += (size_t)BB * CHUNKS * DII * NSS * 2;  // 6.3 MB

    float* out = (float*)d_out;

    // 0. merged prep (cvt W_in/W_out, build W2/bias2, norm)
    k_prep<<<CVT_BLOCKS + W2_BLOCKS + NORM_BLOCKS, 256, 0, stream>>>(
        W_in, WINH, W_out, WOH, W_x, b_x, W_dt, b_dt, W2H, BIAS2,
        hs, gamma, HSNH);

    // 1. xz = hsn @ W_in^T + b_in (2048 x 3072 x 768); z-half gated in epilogue
    k_gemm128<2, h16><<<dim3(XZN / 128, NROWS / 128), 256, 0, stream>>>(
        HSNH, DMM, WINH, DMM, b_in, XZH, XZN, DMM, nullptr, nullptr);

    // 2. conv + dsp -> f16 xact (8 ch/thread)
    k_conv<<<(NROWS * (DII / 8)) / 256, 256, 0, stream>>>(XZH, conv_w, conv_b, XACTH);

    // 3. combined: [decay_mod | B | C] = xact @ W2^T + bias2 (2048 x 1664 x 1536)
    k_gemm128<0, h16><<<dim3(N2 / 128, NROWS / 128), 256, 0, stream>>>(
        XACTH, DII, W2H, DII, BIAS2, DMBCH, N2, DII, nullptr, nullptr);

    // 4. chunked scan (64 chunks x 16, f16 state) + fused einsum + gate -> ygh
    k_scan_p1<<<BB * CHUNKS * 6, 256, 0, stream>>>(
        DMBCH, XACTH, base_dec, dec_shift, STA, STH);
    k_scan_p2<<<NCH / 64, 64, 0, stream>>>(STA, STH);
    k_scan_p3<<<BB * CHUNKS * 6, 256, 0, stream>>>(
        DMBCH, XACTH, XZH, base_dec, dec_shift, STA, YGH);

    // 5. out = resid + clip(yg @ W_out^T + b_out)*rg (2048 x 768 x 1536)
    k_gemm64<1, float><<<dim3(DMM / 64, NROWS / 64), 256, 0, stream>>>(
        YGH, DII, WOH, DII, b_out, out, DMM, DII, hs, res_gate);
}

// Round 15
// 153.371 us; speedup vs baseline: 1.0397x; 1.0397x over previous
//
#include <hip/hip_runtime.h>
#include <hip/hip_bf16.h>
#include <stdint.h>

// Problem constants
#define BB  2
#define LL  1024
#define DMM 768
#define DII 1536
#define NSS 16
#define DTRR 48
#define XZN (2*DII)        // 3072
#define NROWS (BB*LL)      // 2048
#define N2 1664            // padded N for combined GEMM2 (1536 dmod + 32 B/C + 96 pad)

// chunked scan: one thread per (b, d, chunk), 16 n-states in registers
#define CHUNKS 64
#define CHLEN  (LL/CHUNKS)          // 16
#define NCH    (BB*DII*NSS)         // 49152 channels

typedef _Float16 h16;
typedef __attribute__((ext_vector_type(4))) _Float16 h16x4;
typedef __attribute__((ext_vector_type(8))) _Float16 h16x8;
typedef __attribute__((ext_vector_type(4))) float f32x4;

typedef const __attribute__((address_space(1))) uint32_t gau32;
typedef __attribute__((address_space(3))) uint32_t lau32;
#define GLL16(gp, lp) __builtin_amdgcn_global_load_lds((gau32*)(gp), (lau32*)(lp), 16, 0, 0)

__device__ __forceinline__ float dspf(float x) {
    return 0.25f * (x + sqrtf(x*x + 4.0f));
}
__device__ __forceinline__ float clampf(float x, float lo, float hi) {
    return fminf(fmaxf(x, lo), hi);
}

// ---------------------------------------------------------------------------
// K0: merged prep = {W_in,W_out -> f16 (vectorized x4)} + {W2/bias2} + {norm}
// ---------------------------------------------------------------------------
#define CVT_BLOCKS ((XZN*DMM + DMM*DII)/4/256)  // 3456
#define W2_BLOCKS  N2                           // 1664
#define NORM_BLOCKS (NROWS/4)                   // 512

__global__ __launch_bounds__(256) void k_prep(
    const float* __restrict__ W_in,  h16* __restrict__ WINH,
    const float* __restrict__ W_out, h16* __restrict__ WOH,
    const float* __restrict__ W_x,   const float* __restrict__ b_x,
    const float* __restrict__ W_dt,  const float* __restrict__ b_dt,
    h16* __restrict__ W2, float* __restrict__ bias2,
    const float* __restrict__ hs, const float* __restrict__ gamma,
    h16* __restrict__ HSNH)
{
    __shared__ float wd[DTRR];
    int blk = blockIdx.x;
    int tid = threadIdx.x;

    if (blk < CVT_BLOCKS) {
        int i4 = blk * 256 + tid;
        const int n14 = (XZN * DMM) / 4;
        const float* src; h16* dst; int o4;
        if (i4 < n14) { src = W_in;  dst = WINH; o4 = i4; }
        else          { src = W_out; dst = WOH;  o4 = i4 - n14; }
        float4 v = *(const float4*)&src[(size_t)o4 * 4];
        h16x4 o = { (h16)v.x, (h16)v.y, (h16)v.z, (h16)v.w };
        *(h16x4*)&dst[(size_t)o4 * 4] = o;
        return;
    }
    blk -= CVT_BLOCKS;
    if (blk < W2_BLOCKS) {
        int i = blk;
        if (i < DII) {
            if (tid < DTRR) wd[tid] = W_dt[i * DTRR + tid];
            __syncthreads();
            for (int j = tid; j < DII; j += 256) {
                float s = 0.f;
                #pragma unroll
                for (int k = 0; k < DTRR; ++k) s = fmaf(wd[k], W_x[(size_t)k * DII + j], s);
                W2[(size_t)i * DII + j] = (h16)s;
            }
            if (tid == 0) {
                float s = b_dt[i];
                for (int k = 0; k < DTRR; ++k) s = fmaf(wd[k], b_x[k], s);
                bias2[i] = s;
            }
        } else if (i < DII + 2 * NSS) {
            int r = i - DII;
            for (int j = tid; j < DII; j += 256)
                W2[(size_t)i * DII + j] = (h16)W_x[(size_t)(DTRR + r) * DII + j];
            if (tid == 0) bias2[i] = b_x[DTRR + r];
        } else {
            for (int j = tid; j < DII; j += 256) W2[(size_t)i * DII + j] = (h16)0.f;
            if (tid == 0) bias2[i] = 0.f;
        }
        return;
    }
    blk -= W2_BLOCKS;
    // norm: wave-per-row, 4 rows/block
    int row  = blk * 4 + (tid >> 6);
    int lane = tid & 63;
    const float* p = hs + (size_t)row * DMM;
    float4 v0 = *(const float4*)&p[lane * 4];
    float4 v1 = *(const float4*)&p[256 + lane * 4];
    float4 v2 = *(const float4*)&p[512 + lane * 4];
    float s = v0.x+v0.y+v0.z+v0.w + v1.x+v1.y+v1.z+v1.w + v2.x+v2.y+v2.z+v2.w;
    #pragma unroll
    for (int off = 32; off > 0; off >>= 1) s += __shfl_xor(s, off);
    float mean = s * (1.0f / (float)DMM);
    float vv = 0.f;
    #pragma unroll
    for (int q = 0; q < 4; ++q) {
        float d0 = ((const float*)&v0)[q] - mean; vv += d0*d0;
        float d1 = ((const float*)&v1)[q] - mean; vv += d1*d1;
        float d2 = ((const float*)&v2)[q] - mean; vv += d2*d2;
    }
    #pragma unroll
    for (int off = 32; off > 0; off >>= 1) vv += __shfl_xor(vv, off);
    float var = vv * (1.0f / (float)DMM);
    float k = rintf(log2f(sqrtf(var + 1e-9f)));
    k = fmaxf(k, 0.f);
    float scale = exp2f(-k);
    float4 g0 = *(const float4*)&gamma[lane * 4];
    float4 g1 = *(const float4*)&gamma[256 + lane * 4];
    float4 g2 = *(const float4*)&gamma[512 + lane * 4];
    h16* o = HSNH + (size_t)row * DMM;
    #pragma unroll
    for (int q = 0; q < 4; ++q) {
        o[lane*4 + q]       = (h16)((((const float*)&v0)[q] - mean) * scale * ((const float*)&g0)[q]);
        o[256 + lane*4 + q] = (h16)((((const float*)&v1)[q] - mean) * scale * ((const float*)&g1)[q]);
        o[512 + lane*4 + q] = (h16)((((const float*)&v2)[q] - mean) * scale * ((const float*)&g2)[q]);
    }
}

// ---------------------------------------------------------------------------
// MFMA f16 GEMM, 128x128 tile, BK=64, double-buffered LDS, vmcnt(8), XCD swz.
// EPI: 0 = plain out; 1 = resid + clip(acc+bias)*rg; 2 = gate() on cols>=DII.
// ---------------------------------------------------------------------------
template<int EPI, typename OutT>
__global__ __launch_bounds__(256) void k_gemm128(
    const h16* __restrict__ A, int lda,
    const h16* __restrict__ Bw, int ldb,
    const float* __restrict__ bias,
    OutT* __restrict__ C, int ldc, int K,
    const float* __restrict__ resid, const float* __restrict__ rgate)
{
    __shared__ __align__(16) h16 As[2][128 * 64];
    __shared__ __align__(16) h16 Bs[2][128 * 64];
    const int tid  = threadIdx.x;
    const int lane = tid & 63;
    const int wv   = tid >> 6;

    const int nwg = gridDim.x * gridDim.y;
    const int bid = blockIdx.y * gridDim.x + blockIdx.x;
    const int cpx = nwg >> 3;
    const int swz = (bid & 7) * cpx + (bid >> 3);
    const int bxi = swz % gridDim.x, byi = swz / gridDim.x;

    const int bm = byi * 128, bn = bxi * 128;
    const int wr = wv >> 1, wc = wv & 1;

    f32x4 acc[4][4] = {};

    const int srow = lane >> 3;
    const int kbl  = ((lane & 7) ^ srow) * 8;
    const int KT = K / 64;

#define STAGE128(dstbuf, k0) do { \
    _Pragma("unroll") \
    for (int q = 0; q < 4; ++q) { \
        int row_ = (wv * 4 + q) * 8 + srow; \
        GLL16(A  + (size_t)(bm + row_) * lda + (k0) + kbl, &As[dstbuf][(wv*4+q)*8*64]); \
        GLL16(Bw + (size_t)(bn + row_) * ldb + (k0) + kbl, &Bs[dstbuf][(wv*4+q)*8*64]); \
    } } while (0)

    STAGE128(0, 0);
    int buf = 0;
    const int r16 = lane & 15, kq = lane >> 4;

    for (int kt = 0; kt < KT; ++kt) {
        if (kt + 1 < KT) {
            STAGE128(buf ^ 1, (kt + 1) * 64);
            asm volatile("s_waitcnt vmcnt(8)" ::: "memory");
        } else {
            asm volatile("s_waitcnt vmcnt(0)" ::: "memory");
        }
        __syncthreads();
        #pragma unroll
        for (int kk = 0; kk < 2; ++kk) {
            h16x8 af[4], bf[4];
            #pragma unroll
            for (int i = 0; i < 4; ++i) {
                int rowA = wr * 64 + i * 16 + r16;
                af[i] = *(const h16x8*)&As[buf][rowA * 64 + (((kk*4 + kq) ^ (rowA & 7)) << 3)];
            }
            #pragma unroll
            for (int j = 0; j < 4; ++j) {
                int rowB = wc * 64 + j * 16 + r16;
                bf[j] = *(const h16x8*)&Bs[buf][rowB * 64 + (((kk*4 + kq) ^ (rowB & 7)) << 3)];
            }
            #pragma unroll
            for (int i = 0; i < 4; ++i)
                #pragma unroll
                for (int j = 0; j < 4; ++j)
                    acc[i][j] = __builtin_amdgcn_mfma_f32_16x16x32_f16(af[i], bf[j], acc[i][j], 0, 0, 0);
        }
        __syncthreads();
        buf ^= 1;
    }
#undef STAGE128

    const int r4 = (lane >> 4) * 4;
    const int cn = lane & 15;
    float rg = 0.f;
    if (EPI == 1) rg = rgate[0];
    #pragma unroll
    for (int i = 0; i < 4; ++i) {
        #pragma unroll
        for (int j = 0; j < 4; ++j) {
            int col = bn + wc * 64 + j * 16 + cn;
            float bv = bias[col];
            #pragma unroll
            for (int r = 0; r < 4; ++r) {
                int row = bm + wr * 64 + i * 16 + r4 + r;
                float v = acc[i][j][r] + bv;
                if (EPI == 1) {
                    v = clampf(v, -32000.f, 32000.f);
                    v = resid[(size_t)row * ldc + col] + v * rg;
                }
                if (EPI == 2) {
                    if (col >= DII) v = 0.5f * (1.0f + v * rsqrtf(v * v + 1.0f));
                }
                C[(size_t)row * ldc + col] = (OutT)v;
            }
        }
    }
}

// ---------------------------------------------------------------------------
// MFMA f16 GEMM, 64x64 tile (proven) for the small-N gemm3.
// ---------------------------------------------------------------------------
template<int EPI, typename OutT>
__global__ __launch_bounds__(256) void k_gemm64(
    const h16* __restrict__ A, int lda,
    const h16* __restrict__ Bw, int ldb,
    const float* __restrict__ bias,
    OutT* __restrict__ C, int ldc, int K,
    const float* __restrict__ resid, const float* __restrict__ rgate)
{
    __shared__ __align__(16) h16 As[2][64 * 64];
    __shared__ __align__(16) h16 Bs[2][64 * 64];
    const int tid  = threadIdx.x;
    const int lane = tid & 63;
    const int wv   = tid >> 6;

    const int nwg = gridDim.x * gridDim.y;
    const int bid = blockIdx.y * gridDim.x + blockIdx.x;
    const int cpx = nwg >> 3;
    const int swz = (bid & 7) * cpx + (bid >> 3);
    const int bxi = swz % gridDim.x, byi = swz / gridDim.x;

    const int bm = byi * 64, bn = bxi * 64;
    const int wr = wv >> 1, wc = wv & 1;

    f32x4 acc[2][2] = {};

    const int srow = lane >> 3;
    const int kbl  = ((lane & 7) ^ srow) * 8;
    const int KT = K / 64;

    #pragma unroll
    for (int q = 0; q < 2; ++q) {
        int row = (wv * 2 + q) * 8 + srow;
        GLL16(A  + (size_t)(bm + row) * lda + kbl, &As[0][(wv*2+q)*8*64]);
        GLL16(Bw + (size_t)(bn + row) * ldb + kbl, &Bs[0][(wv*2+q)*8*64]);
    }

    int buf = 0;
    for (int kt = 0; kt < KT; ++kt) {
        if (kt + 1 < KT) {
            int k0 = (kt + 1) * 64;
            #pragma unroll
            for (int q = 0; q < 2; ++q) {
                int row = (wv * 2 + q) * 8 + srow;
                GLL16(A  + (size_t)(bm + row) * lda + k0 + kbl, &As[buf^1][(wv*2+q)*8*64]);
                GLL16(Bw + (size_t)(bn + row) * ldb + k0 + kbl, &Bs[buf^1][(wv*2+q)*8*64]);
            }
            asm volatile("s_waitcnt vmcnt(4)" ::: "memory");
        } else {
            asm volatile("s_waitcnt vmcnt(0)" ::: "memory");
        }
        __syncthreads();

        const int r16 = lane & 15, kq = lane >> 4;
        #pragma unroll
        for (int kk = 0; kk < 2; ++kk) {
            h16x8 af[2], bf[2];
            #pragma unroll
            for (int i = 0; i < 2; ++i) {
                int rowA = wr * 32 + i * 16 + r16;
                af[i] = *(const h16x8*)&As[buf][rowA * 64 + (((kk*4 + kq) ^ (rowA & 7)) << 3)];
            }
            #pragma unroll
            for (int j = 0; j < 2; ++j) {
                int rowB = wc * 32 + j * 16 + r16;
                bf[j] = *(const h16x8*)&Bs[buf][rowB * 64 + (((kk*4 + kq) ^ (rowB & 7)) << 3)];
            }
            #pragma unroll
            for (int i = 0; i < 2; ++i)
                #pragma unroll
                for (int j = 0; j < 2; ++j)
                    acc[i][j] = __builtin_amdgcn_mfma_f32_16x16x32_f16(af[i], bf[j], acc[i][j], 0, 0, 0);
        }
        __syncthreads();
        buf ^= 1;
    }

    const int r4 = (lane >> 4) * 4;
    const int cn = lane & 15;
    float rg = 0.f;
    if (EPI == 1) rg = rgate[0];
    #pragma unroll
    for (int i = 0; i < 2; ++i) {
        #pragma unroll
        for (int j = 0; j < 2; ++j) {
            int col = bn + wc * 32 + j * 16 + cn;
            float bv = bias[col];
            #pragma unroll
            for (int r = 0; r < 4; ++r) {
                int row = bm + wr * 32 + i * 16 + r4 + r;
                float v = acc[i][j][r] + bv;
                if (EPI == 1) {
                    v = clampf(v, -32000.f, 32000.f);
                    v = resid[(size_t)row * ldc + col] + v * rg;
                }
                C[(size_t)row * ldc + col] = (OutT)v;
            }
        }
    }
}

// ---------------------------------------------------------------------------
// K3: depthwise causal conv (f16 in) + dsp -> f16 xact, 8 channels/thread
// ---------------------------------------------------------------------------
__global__ __launch_bounds__(256) void k_conv(const h16* __restrict__ xz,
                                              const float* __restrict__ cw,
                                              const float* __restrict__ cb,
                                              h16* __restrict__ xacth)
{
    int idx = blockIdx.x * 256 + threadIdx.x;       // over NROWS * (DII/8)
    if (idx >= NROWS * (DII / 8)) return;
    int c8 = idx % (DII / 8);
    int bl = idx / (DII / 8);
    int l = bl % LL;
    int b = bl / LL;
    int c0 = c8 * 8;

    float acc[8];
    float4 wv[8];
    #pragma unroll
    for (int j = 0; j < 8; ++j) {
        acc[j] = cb[c0 + j];
        wv[j] = *(const float4*)&cw[(c0 + j) * 4];
    }
    #pragma unroll
    for (int t = 0; t < 4; ++t) {
        int ls = l - 3 + t;
        if (ls >= 0) {
            h16x8 xv = *(const h16x8*)&xz[(size_t)(b * LL + ls) * XZN + c0];
            #pragma unroll
            for (int j = 0; j < 8; ++j)
                acc[j] = fmaf((float)xv[j], ((const float*)&wv[j])[t], acc[j]);
        }
    }
    h16x8 o;
    #pragma unroll
    for (int j = 0; j < 8; ++j) o[j] = (h16)dspf(acc[j]);
    *(h16x8*)&xacth[(size_t)bl * DII + c0] = o;
}

// ---------------------------------------------------------------------------
// Chunked scan (round-11 structure), f16 STATE (halved traffic).
// a = clip(base+dm,0,32767)*2^-s == fma(dm, p2c, base*p2c) (clip never binds).
// ---------------------------------------------------------------------------
__device__ __forceinline__ void load_setup(const float* __restrict__ basenum,
                                           const int* __restrict__ shifts,
                                           int d, float* baseP, float* p2c) {
    const float4* bp = (const float4*)(basenum + (size_t)d * NSS);
    const int4*   sp = (const int4*)(shifts + (size_t)d * NSS);
    #pragma unroll
    for (int q = 0; q < 4; ++q) {
        float4 bv = bp[q]; int4 sv = sp[q];
        p2c[q*4+0] = exp2f(-(float)sv.x);
        p2c[q*4+1] = exp2f(-(float)sv.y);
        p2c[q*4+2] = exp2f(-(float)sv.z);
        p2c[q*4+3] = exp2f(-(float)sv.w);
        baseP[q*4+0] = bv.x * p2c[q*4+0];
        baseP[q*4+1] = bv.y * p2c[q*4+1];
        baseP[q*4+2] = bv.z * p2c[q*4+2];
        baseP[q*4+3] = bv.w * p2c[q*4+3];
    }
}

__global__ __launch_bounds__(256) void k_scan_p1(
    const h16* __restrict__ dmbc,      // (B*L, N2) f16: [dmod 1536 | B 16 | C 16 | pad]
    const h16* __restrict__ xacth,     // (B*L, DI)
    const float* __restrict__ basenum, // (DI, NS)
    const int*   __restrict__ shifts,  // (DI, NS)
    h16* __restrict__ stA, h16* __restrict__ stH)
{
    int bc   = blockIdx.x / 6;              // b*CHUNKS + chunk  (uniform)
    int dblk = blockIdx.x % 6;
    int d    = dblk * 256 + threadIdx.x;
    int b    = bc / CHUNKS;
    int chunk= bc % CHUNKS;

    float baseP[16], p2c[16], h[16], A[16];
    load_setup(basenum, shifts, d, baseP, p2c);
    #pragma unroll
    for (int n = 0; n < 16; ++n) { h[n] = 0.f; A[n] = 1.f; }

    int row0 = b * LL + chunk * CHLEN;
    #pragma unroll 4
    for (int l = 0; l < CHLEN; ++l) {
        int row = row0 + l;
        float dm = (float)dmbc[(size_t)row * N2 + d];
        float xv = (float)xacth[(size_t)row * DII + d];
        float common = xv * (dspf(dm) * 0.1f);
        const h16x8* Bp = (const h16x8*)(dmbc + (size_t)row * N2 + DII);
        h16x8 b0 = Bp[0], b1 = Bp[1];
        float Bv[16];
        #pragma unroll
        for (int n = 0; n < 8; ++n) { Bv[n] = (float)b0[n]; Bv[8+n] = (float)b1[n]; }
        #pragma unroll
        for (int n = 0; n < 16; ++n) {
            float a = fmaf(dm, p2c[n], baseP[n]);
            h[n] = fmaf(a, h[n], common * Bv[n]);
            A[n] *= a;
        }
    }
    size_t sb = ((size_t)bc * DII + d) * 16;
    h16x8 a0, a1, h0, h1;
    #pragma unroll
    for (int n = 0; n < 8; ++n) {
        a0[n] = (h16)A[n];   a1[n] = (h16)A[8+n];
        h0[n] = (h16)h[n];   h1[n] = (h16)h[8+n];
    }
    *(h16x8*)&stA[sb]     = a0;
    *(h16x8*)&stA[sb + 8] = a1;
    *(h16x8*)&stH[sb]     = h0;
    *(h16x8*)&stH[sb + 8] = h1;
}

__global__ __launch_bounds__(64) void k_scan_p2(h16* __restrict__ stA,
                                                const h16* __restrict__ stH)
{
    int ch = blockIdx.x * 64 + threadIdx.x;    // b*(DII*NSS) + d*16 + n
    int b  = ch / (DII * NSS);
    int rem = ch - b * (DII * NSS);
    float hin = 0.f;
    #pragma unroll 4
    for (int c = 0; c < CHUNKS; ++c) {
        size_t idx = ((size_t)(b * CHUNKS + c) * (DII * NSS)) + rem;
        float a = (float)stA[idx], hh = (float)stH[idx];
        stA[idx] = (h16)hin;
        hin = fmaf(a, hin, hh);
    }
}

__global__ __launch_bounds__(256) void k_scan_p3(
    const h16* __restrict__ dmbc,
    const h16* __restrict__ xacth,
    const h16* __restrict__ xz,        // z-half already gate-transformed
    const float* __restrict__ basenum,
    const int*   __restrict__ shifts,
    const h16* __restrict__ stA,
    h16* __restrict__ ygh)             // (B*L, DI) = y * gate(z), f16
{
    int bc   = blockIdx.x / 6;
    int dblk = blockIdx.x % 6;
    int d    = dblk * 256 + threadIdx.x;
    int b    = bc / CHUNKS;
    int chunk= bc % CHUNKS;

    float baseP[16], p2c[16], h[16];
    load_setup(basenum, shifts, d, baseP, p2c);
    size_t sb = ((size_t)bc * DII + d) * 16;
    {
        h16x8 p0 = *(const h16x8*)&stA[sb];
        h16x8 p1 = *(const h16x8*)&stA[sb + 8];
        #pragma unroll
        for (int n = 0; n < 8; ++n) { h[n] = (float)p0[n]; h[8+n] = (float)p1[n]; }
    }

    int row0 = b * LL + chunk * CHLEN;
    #pragma unroll 4
    for (int l = 0; l < CHLEN; ++l) {
        int row = row0 + l;
        float dm = (float)dmbc[(size_t)row * N2 + d];
        float xv = (float)xacth[(size_t)row * DII + d];
        float common = xv * (dspf(dm) * 0.1f);
        const h16x8* Bp = (const h16x8*)(dmbc + (size_t)row * N2 + DII);
        h16x8 b0 = Bp[0], b1 = Bp[1], c0 = Bp[2], c1 = Bp[3];
        float Bv[16], Cv[16];
        #pragma unroll
        for (int n = 0; n < 8; ++n) {
            Bv[n] = (float)b0[n]; Bv[8+n] = (float)b1[n];
            Cv[n] = (float)c0[n]; Cv[8+n] = (float)c1[n];
        }
        float y = 0.f;
        #pragma unroll
        for (int n = 0; n < 16; ++n) {
            float a = fmaf(dm, p2c[n], baseP[n]);
            h[n] = fmaf(a, h[n], common * Bv[n]);
            float hc = clampf(h[n], -32000.f, 32000.f);
            y = fmaf(hc, Cv[n], y);
        }
        float gate = (float)xz[(size_t)row * XZN + DII + d];   // pre-gated
        ygh[(size_t)row * DII + d] = (h16)(y * gate);
    }
}

// ---------------------------------------------------------------------------
extern "C" void kernel_launch(void* const* d_in, const int* in_sizes, int n_in,
                              void* d_out, int out_size, void* d_ws, size_t ws_size,
                              hipStream_t stream) {
    const float* hs        = (const float*)d_in[0];
    const float* gamma     = (const float*)d_in[1];
    const float* W_in      = (const float*)d_in[2];
    const float* b_in      = (const float*)d_in[3];
    const float* conv_w    = (const float*)d_in[4];
    const float* conv_b    = (const float*)d_in[5];
    const float* W_x       = (const float*)d_in[6];
    const float* b_x       = (const float*)d_in[7];
    const float* W_dt      = (const float*)d_in[8];
    const float* b_dt      = (const float*)d_in[9];
    const float* W_out     = (const float*)d_in[10];
    const float* b_out     = (const float*)d_in[11];
    const float* base_dec  = (const float*)d_in[12];
    const float* res_gate  = (const float*)d_in[13];
    const int*   dec_shift = (const int*)d_in[14];

    // workspace layout (bytes)
    char* w = (char*)d_ws;
    h16*   XZH   = (h16*)w;    w += (size_t)NROWS * XZN * 2;   // 12.6 MB (x | gate(z))
    h16*   XACTH = (h16*)w;    w += (size_t)NROWS * DII * 2;   //  6.3 MB
    h16*   DMBCH = (h16*)w;    w += (size_t)NROWS * N2  * 2;   //  6.8 MB
    h16*   W2H   = (h16*)w;    w += (size_t)N2 * DII * 2;      //  5.1 MB
    h16*   WOH   = (h16*)w;    w += (size_t)DMM * DII * 2;     //  2.4 MB
    float* BIAS2 = (float*)w;  w += 8192;
    h16*   YGH   = (h16*)w;    w += (size_t)NROWS * DII * 2;   //  6.3 MB
    h16*   HSNH  = (h16*)w;    w += (size_t)NROWS * DMM * 2;   //  3.1 MB
    h16*   WINH  = (h16*)w;    w += (size_t)XZN * DMM * 2;     //  4.7 MB
    h16*   STA   = (h16*)w;    w += (size_t)BB * CHUNKS * DII * NSS * 2;  // 6.3 MB
    h16*   STH   = (h16*)w;    w += (size_t)BB * CHUNKS * DII * NSS * 2;  // 6.3 MB

    float* out = (float*)d_out;

    // 0. merged prep (cvt W_in/W_out, build W2/bias2, norm)
    k_prep<<<CVT_BLOCKS + W2_BLOCKS + NORM_BLOCKS, 256, 0, stream>>>(
        W_in, WINH, W_out, WOH, W_x, b_x, W_dt, b_dt, W2H, BIAS2,
        hs, gamma, HSNH);

    // 1. xz = hsn @ W_in^T + b_in (2048 x 3072 x 768); z-half gated in epilogue
    k_gemm128<2, h16><<<dim3(XZN / 128, NROWS / 128), 256, 0, stream>>>(
        HSNH, DMM, WINH, DMM, b_in, XZH, XZN, DMM, nullptr, nullptr);

    // 2. conv + dsp -> f16 xact (8 ch/thread)
    k_conv<<<(NROWS * (DII / 8)) / 256, 256, 0, stream>>>(XZH, conv_w, conv_b, XACTH);

    // 3. combined: [decay_mod | B | C] = xact @ W2^T + bias2 (2048 x 1664 x 1536)
    k_gemm128<0, h16><<<dim3(N2 / 128, NROWS / 128), 256, 0, stream>>>(
        XACTH, DII, W2H, DII, BIAS2, DMBCH, N2, DII, nullptr, nullptr);

    // 4. chunked scan (64 chunks x 16, f16 state) + fused einsum + gate -> ygh
    k_scan_p1<<<BB * CHUNKS * 6, 256, 0, stream>>>(
        DMBCH, XACTH, base_dec, dec_shift, STA, STH);
    k_scan_p2<<<NCH / 64, 64, 0, stream>>>(STA, STH);
    k_scan_p3<<<BB * CHUNKS * 6, 256, 0, stream>>>(
        DMBCH, XACTH, XZH, base_dec, dec_shift, STA, YGH);

    // 5. out = resid + clip(yg @ W_out^T + b_out)*rg (2048 x 768 x 1536)
    k_gemm64<1, float><<<dim3(DMM / 64, NROWS / 64), 256, 0, stream>>>(
        YGH, DII, WOH, DII, b_out, out, DMM, DII, hs, res_gate);
}